// Round 18
// baseline (284.257 us; speedup 1.0000x reference)
//
#include <hip/hip_runtime.h>
#include <math.h>
#include <stdint.h>

#define NPTS 262144
#define KCL  256
#define DDIM 64
#define ALPHA_DP 1.0f

#define ROWS_PER_WAVE 32
#define WAVES_PER_BLK 4
#define ROWS_PER_BLK  (ROWS_PER_WAVE * WAVES_PER_BLK)   // 128
#define NBLK_MAIN     (NPTS / ROWS_PER_BLK)             // 2048
#define NPART         (NPTS / ROWS_PER_WAVE)            // 8192

// ws float offsets
#define OFF_ELOGPI 32768
#define OFF_BASE   33024
#define OFF_KLB    33280
#define OFF_KLP    33281
#define OFF_PART   33537
#define OFF_CNT    (OFF_PART + NPART)   // 41729: block-done counter (uint)

#define LN2_F    0.6931471805599453f
#define LOG2PI_F 1.8378770664093453f

typedef _Float16 f16x8  __attribute__((ext_vector_type(8)));
typedef float    f32x4  __attribute__((ext_vector_type(4)));
typedef float    f32x16 __attribute__((ext_vector_type(16)));

__device__ __forceinline__ float digamma_f(float x) {
  float r = 0.0f;
  while (x < 6.0f) { r -= 1.0f / x; x += 1.0f; }
  float inv  = 1.0f / x;
  float inv2 = inv * inv;
  return r + logf(x) - 0.5f * inv
       - inv2 * (0.083333333333333333f
         - inv2 * (0.008333333333333333f
           - inv2 * 0.003968253968253968f));
}

// --- fused prep (one launch): blocks 0..255 W-split, block 256 beta --------
// beta and W-split are independent (base excludes elogpi; mfma adds it).
// Frag layout: frag fi (0..63 Wh, 64..127 Wl), fi%64 = s*8 + ct, s=krow>>4.
//   element: Wp[fi*512 + lane*8 + e];  b-frag: col=lane&31, k=(lane>>5)*8+e
// Cluster k at tile ct=k&7, col=k>>3 -> lane owns 8 contiguous pi columns.
__global__ __launch_bounds__(64) void dpmm_prep(
    const float* __restrict__ u,   const float* __restrict__ v,
    const float* __restrict__ tau, const float* __restrict__ c,
    const float* __restrict__ n,   const float* __restrict__ B,
    const float* __restrict__ tau0, const float* __restrict__ c0,
    const float* __restrict__ n0,  const float* __restrict__ B0,
    float* __restrict__ ws) {
  const int tid = threadIdx.x;

  if (blockIdx.x == KCL) {
    // ---- beta block: thread t owns clusters 4t..4t+3 ----
    if (tid == 0) ((unsigned int*)ws)[OFF_CNT] = 0u;   // reset done-counter
    float eb[4], e1b[4], klb[4];
    #pragma unroll
    for (int q = 0; q < 4; ++q) {
      int k = tid * 4 + q;
      float uk = u[k], vk = v[k];
      float ds = digamma_f(uk + vk);
      eb[q]  = digamma_f(uk) - ds;
      e1b[q] = digamma_f(vk) - ds;
      klb[q] = lgammaf(uk + vk) - lgammaf(uk) - lgammaf(vk)
             - (lgammaf(1.0f + ALPHA_DP) - lgammaf(ALPHA_DP))
             + (uk - 1.0f) * eb[q] + (vk - ALPHA_DP) * e1b[q];
    }
    float sum4 = e1b[0] + e1b[1] + e1b[2] + e1b[3];
    float sc = sum4;
    #pragma unroll
    for (int off = 1; off < 64; off <<= 1) {
      float vv = __shfl_up(sc, off, 64);
      if (tid >= off) sc += vv;
    }
    float pre = sc - sum4;                       // exclusive prefix
    ws[OFF_ELOGPI + 4 * tid + 0] = eb[0] + pre;  pre += e1b[0];
    ws[OFF_ELOGPI + 4 * tid + 1] = eb[1] + pre;  pre += e1b[1];
    ws[OFF_ELOGPI + 4 * tid + 2] = eb[2] + pre;  pre += e1b[2];
    ws[OFF_ELOGPI + 4 * tid + 3] = eb[3] + pre;
    float ks = klb[0] + klb[1] + klb[2] + klb[3];
    #pragma unroll
    for (int off = 32; off; off >>= 1) ks += __shfl_xor(ks, off, 64);
    if (tid == 0) ws[OFF_KLB] = ks;
    return;
  }

  // ---- W-split block (one cluster) ----
  const int k = blockIdx.x, d = tid;
  _Float16* Wp = (_Float16*)ws;

  float nk = n[k], ck = c[k], n0k = n0[k], c0k = c0[k];
  float Bkd = B[k * DDIM + d],   tkd  = tau[k * DDIM + d];
  float B0kd = B0[k * DDIM + d], t0kd = tau0[k * DDIM + d];
  float Elam = nk / Bkd;
  float wb = Elam * tkd;        // coeff of x   (krow d)
  float wa = -0.5f * Elam;      // coeff of x^2 (krow 64+d)

  const int ct = k & 7, col = k >> 3;
  int   kks[2] = { d, 64 + d };
  float wvs[2] = { wb, wa };
  #pragma unroll
  for (int q = 0; q < 2; ++q) {
    int kk = kks[q]; float wq = wvs[q];
    int s = kk >> 4, rem = kk & 15, h = rem >> 3, e = rem & 7;
    int lanei = col + h * 32;
    _Float16 hi = (_Float16)wq, lo = (_Float16)(wq - (float)hi);
    Wp[( s * 8 + ct)     * 512 + lanei * 8 + e] = hi;
    Wp[(64 + s * 8 + ct) * 512 + lanei * 8 + e] = lo;
  }

  float a = 0.5f * nk, a0 = 0.5f * n0k;
  float dga = digamma_f(a);
  float lga = lgammaf(a), lga0 = lgammaf(a0);
  float b = 0.5f * Bkd, b0 = 0.5f * B0kd;
  float klg = (a - a0) * dga - lga + lga0
            + a0 * (logf(b) - logf(b0)) + a * (b0 - b) / b;
  float dt = tkd - t0kd;
  float knq = Elam * dt * dt;
  float negLogB = -logf(Bkd);
  float et2 = Elam * tkd * tkd;

  #pragma unroll
  for (int off = 32; off; off >>= 1) {
    klg     += __shfl_xor(klg, off, 64);
    knq     += __shfl_xor(knq, off, 64);
    negLogB += __shfl_xor(negLogB, off, 64);
    et2     += __shfl_xor(et2, off, 64);
  }
  if (d == 0) {
    float sumEloglam = (float)DDIM * (dga + LN2_F) + negLogB;
    ws[OFF_BASE + k] = 0.5f * (sumEloglam - (float)DDIM * LOG2PI_F
                               - (float)DDIM / ck - et2);   // NO elogpi here
    float kln = 0.5f * (float)DDIM * (c0k / ck - 1.0f + logf(ck / c0k))
              + 0.5f * c0k * knq;
    ws[OFF_KLP + k] = klg + kln;
  }
}

__device__ __forceinline__ void split8(const float* v, f16x8& h, f16x8& l) {
  #pragma unroll
  for (int e = 0; e < 8; ++e) {
    _Float16 hh = (_Float16)v[e];
    h[e] = hh;
    l[e] = (_Float16)(v[e] - (float)hh);
  }
}

// direct global->LDS DMA, 16B per lane; LDS dest = wave-uniform base + lane*16
__device__ __forceinline__ void gload16(const _Float16* g, _Float16* l) {
  __builtin_amdgcn_global_load_lds(
      reinterpret_cast<const __attribute__((address_space(1))) uint32_t*>(
          reinterpret_cast<uintptr_t>(g)),
      reinterpret_cast<__attribute__((address_space(3))) uint32_t*>(
          reinterpret_cast<uintptr_t>(l)),
      16, 0, 0);
}

// R16 main (verified: total 114.9us): 32x32x16 MFMA, 32 rows/wave, W staged
// via global_load_lds in 4x 32KB chunks double-buffered (64 KB LDS,
// 2 blocks/CU). New: fin fused via deterministic last-block reduction.
__global__ __launch_bounds__(256, 2) void dpmm_mfma(
    const float* __restrict__ x, float* __restrict__ ws,
    float* __restrict__ pi, float* __restrict__ out_elbo) {
  __shared__ _Float16 W_sh[2][16384];           // 2 x 32KB chunk buffers
  const _Float16* Wp     = (const _Float16*)ws;
  const float* base      = ws + OFF_BASE;
  const float* elogpi    = ws + OFF_ELOGPI;
  float* partial         = ws + OFF_PART;
  const int tid  = threadIdx.x;
  const int lane = tid & 63;
  const int w    = tid >> 6;
  const int col  = lane & 31;                   // tile col / A row
  const int h    = lane >> 5;                   // k-half

  // ---- x loads first (in flight during chunk0 DMA) ----
  const long row0 = (long)blockIdx.x * ROWS_PER_BLK + (long)w * ROWS_PER_WAVE;
  const float* xr = x + (row0 + col) * DDIM + h * 8;
  float4 xa[4], xb[4];
  #pragma unroll
  for (int s = 0; s < 4; ++s) {
    xa[s] = *(const float4*)(xr + s * 16);
    xb[s] = *(const float4*)(xr + s * 16 + 4);
  }

  // ---- issue chunk0 DMA ----
  #pragma unroll
  for (int i = 0; i < 8; ++i)
    gload16(Wp + (i * 256 + tid) * 8, &W_sh[0][(i * 256 + w * 64) * 8]);

  // ---- A fragments: s=0..3 x, s=4..7 x^2 (hi/lo) ----
  f16x8 ah[8], al[8];
  #pragma unroll
  for (int s = 0; s < 4; ++s) {
    float cv[8] = {xa[s].x,xa[s].y,xa[s].z,xa[s].w,xb[s].x,xb[s].y,xb[s].z,xb[s].w};
    float qv[8];
    #pragma unroll
    for (int e = 0; e < 8; ++e) qv[e] = cv[e] * cv[e];
    split8(cv, ah[s], al[s]);
    split8(qv, ah[s + 4], al[s + 4]);
  }

  // ---- acc init: base + elogpi (cluster col*8+ct) ----
  f32x16 acc[8];
  {
    float4 b0 = *(const float4*)(base + col * 8);
    float4 b1 = *(const float4*)(base + col * 8 + 4);
    float4 e0 = *(const float4*)(elogpi + col * 8);
    float4 e1 = *(const float4*)(elogpi + col * 8 + 4);
    float bb[8] = {b0.x+e0.x, b0.y+e0.y, b0.z+e0.z, b0.w+e0.w,
                   b1.x+e1.x, b1.y+e1.y, b1.z+e1.z, b1.w+e1.w};
    #pragma unroll
    for (int ct = 0; ct < 8; ++ct) {
      #pragma unroll
      for (int j = 0; j < 16; ++j) acc[ct][j] = bb[ct];
    }
  }

  __syncthreads();                              // chunk0 landed

  // ---- chunk loop: chunk c GEMM || chunk c+1 DMA ----
  // chunk 0: Wh s=0..3 (ah+al) | 1: Wh s=4..7 (ah+al) | 2: Wl s=0..3 (ah) |
  // 3: Wl s=4..7 (ah)
  #pragma unroll
  for (int c = 0; c < 4; ++c) {
    if (c + 1 < 4) {
      #pragma unroll
      for (int i = 0; i < 8; ++i)
        gload16(Wp + (size_t)(c + 1) * 16384 + (i * 256 + tid) * 8,
                &W_sh[(c + 1) & 1][(i * 256 + w * 64) * 8]);
    }
    const _Float16* Ws = W_sh[c & 1];
    #pragma unroll
    for (int f = 0; f < 32; ++f) {
      const int ss = f >> 3, ct = f & 7;
      f16x8 b = *(const f16x8*)&Ws[f * 512 + lane * 8];
      if (c == 0) {
        acc[ct] = __builtin_amdgcn_mfma_f32_32x32x16_f16(ah[ss], b, acc[ct], 0, 0, 0);
        acc[ct] = __builtin_amdgcn_mfma_f32_32x32x16_f16(al[ss], b, acc[ct], 0, 0, 0);
      } else if (c == 1) {
        acc[ct] = __builtin_amdgcn_mfma_f32_32x32x16_f16(ah[4 + ss], b, acc[ct], 0, 0, 0);
        acc[ct] = __builtin_amdgcn_mfma_f32_32x32x16_f16(al[4 + ss], b, acc[ct], 0, 0, 0);
      } else if (c == 2) {
        acc[ct] = __builtin_amdgcn_mfma_f32_32x32x16_f16(ah[ss], b, acc[ct], 0, 0, 0);
      } else {
        acc[ct] = __builtin_amdgcn_mfma_f32_32x32x16_f16(ah[4 + ss], b, acc[ct], 0, 0, 0);
      }
    }
    if (c + 1 < 4) __syncthreads();             // drains chunk c+1 DMA
  }

  // ---- softmax epilogue; reg j -> row (j&3)+8*(j>>2)+4*h, lane owns 8 cols ----
  float wls = 0.0f;
  #pragma unroll
  for (int j = 0; j < 16; ++j) {
    const int r = (j & 3) + 8 * (j >> 2) + 4 * h;
    float m = acc[0][j];
    #pragma unroll
    for (int ct = 1; ct < 8; ++ct) m = fmaxf(m, acc[ct][j]);
    m = fmaxf(m, __shfl_xor(m, 1, 64));
    m = fmaxf(m, __shfl_xor(m, 2, 64));
    m = fmaxf(m, __shfl_xor(m, 4, 64));
    m = fmaxf(m, __shfl_xor(m, 8, 64));
    m = fmaxf(m, __shfl_xor(m, 16, 64));
    float ev[8]; float s = 0.0f;
    #pragma unroll
    for (int ct = 0; ct < 8; ++ct) { ev[ct] = __expf(acc[ct][j] - m); s += ev[ct]; }
    s += __shfl_xor(s, 1, 64);
    s += __shfl_xor(s, 2, 64);
    s += __shfl_xor(s, 4, 64);
    s += __shfl_xor(s, 8, 64);
    s += __shfl_xor(s, 16, 64);
    float rs = 1.0f / s;
    float* pr = pi + (size_t)(row0 + r) * KCL + col * 8;
    f32x4 p0 = { ev[0]*rs, ev[1]*rs, ev[2]*rs, ev[3]*rs };
    f32x4 p1 = { ev[4]*rs, ev[5]*rs, ev[6]*rs, ev[7]*rs };
    *(f32x4*)(pr + 0) = p0;
    *(f32x4*)(pr + 4) = p1;
    wls += m + __logf(s);       // identical across the 32 lanes of this row
  }
  wls += __shfl_xor(wls, 1, 64);
  wls += __shfl_xor(wls, 2, 64);
  wls += __shfl_xor(wls, 4, 64);
  wls += __shfl_xor(wls, 8, 64);
  wls += __shfl_xor(wls, 16, 64);
  wls += __shfl_xor(wls, 32, 64);
  if (lane == 0) partial[blockIdx.x * WAVES_PER_BLK + w] = wls * 0.03125f; // /32

  // ---- fused fin: deterministic last-block reduction ----
  __shared__ int isLast;
  __shared__ double red[256];
  __syncthreads();                              // all partial stores issued
  if (tid == 0) {
    __threadfence();                            // publish partials (agent scope)
    unsigned int old = atomicAdd((unsigned int*)ws + OFF_CNT, 1u);
    isLast = (old == (unsigned int)(NBLK_MAIN - 1));
  }
  __syncthreads();
  if (isLast) {
    __threadfence();                            // acquire: see all partials
    double s = 0.0;
    for (int i = tid; i < NPART; i += 256) s += (double)ws[OFF_PART + i];
    s -= (double)ws[OFF_KLP + tid];             // per-cluster KL parts
    red[tid] = s;
    __syncthreads();
    for (int off = 128; off; off >>= 1) {
      if (tid < off) red[tid] += red[tid + off];
      __syncthreads();
    }
    if (tid == 0) out_elbo[0] = (float)(red[0] - (double)ws[OFF_KLB]);
  }
}

extern "C" void kernel_launch(void* const* d_in, const int* in_sizes, int n_in,
                              void* d_out, int out_size, void* d_ws, size_t ws_size,
                              hipStream_t stream) {
  const float* x    = (const float*)d_in[0];
  const float* u    = (const float*)d_in[1];
  const float* v    = (const float*)d_in[2];
  const float* tau  = (const float*)d_in[3];
  const float* c    = (const float*)d_in[4];
  const float* n    = (const float*)d_in[5];
  const float* B    = (const float*)d_in[6];
  const float* tau0 = (const float*)d_in[7];
  const float* c0   = (const float*)d_in[8];
  const float* n0   = (const float*)d_in[9];
  const float* B0   = (const float*)d_in[10];

  float* out = (float*)d_out;
  float* ws  = (float*)d_ws;

  dpmm_prep<<<KCL + 1, 64, 0, stream>>>(u, v, tau, c, n, B, tau0, c0, n0, B0, ws);
  dpmm_mfma<<<NBLK_MAIN, 256, 0, stream>>>(x, ws, out, out + (size_t)NPTS * KCL);
}

// Round 20
// 158.836 us; speedup vs baseline: 1.7896x; 1.7896x over previous
//
#include <hip/hip_runtime.h>
#include <math.h>
#include <stdint.h>

#define NPTS 262144
#define KCL  256
#define DDIM 64
#define ALPHA_DP 1.0f

#define ROWS_PER_BLK  64
#define NBLK_MAIN     (NPTS / ROWS_PER_BLK)             // 4096
#define NPART         (NPTS / 32)                       // 8192

// ws float offsets
#define OFF_ELOGPI 32768
#define OFF_BASE   33024
#define OFF_KLB    33280
#define OFF_KLP    33281
#define OFF_PART   33537

#define LN2_F    0.6931471805599453f
#define LOG2PI_F 1.8378770664093453f

typedef _Float16 f16x8  __attribute__((ext_vector_type(8)));
typedef float    f32x4  __attribute__((ext_vector_type(4)));
typedef float    f32x16 __attribute__((ext_vector_type(16)));

__device__ __forceinline__ float digamma_f(float x) {
  float r = 0.0f;
  while (x < 6.0f) { r -= 1.0f / x; x += 1.0f; }
  float inv  = 1.0f / x;
  float inv2 = inv * inv;
  return r + logf(x) - 0.5f * inv
       - inv2 * (0.083333333333333333f
         - inv2 * (0.008333333333333333f
           - inv2 * 0.003968253968253968f));
}

// --- fused prep (one launch): blocks 0..255 W-split, block 256 beta --------
// Frag layout: frag fi (0..63 Wh, 64..127 Wl), fi%64 = s*8 + ct, s=krow>>4.
//   element: Wp[fi*512 + lane*8 + e];  b-frag: col=lane&31, k=(lane>>5)*8+e
// Cluster k at tile ct=k&7, col=k>>3 -> lane owns 8 contiguous pi columns.
__global__ __launch_bounds__(64) void dpmm_prep(
    const float* __restrict__ u,   const float* __restrict__ v,
    const float* __restrict__ tau, const float* __restrict__ c,
    const float* __restrict__ n,   const float* __restrict__ B,
    const float* __restrict__ tau0, const float* __restrict__ c0,
    const float* __restrict__ n0,  const float* __restrict__ B0,
    float* __restrict__ ws) {
  const int tid = threadIdx.x;

  if (blockIdx.x == KCL) {
    // ---- beta block: thread t owns clusters 4t..4t+3 ----
    float eb[4], e1b[4], klb[4];
    #pragma unroll
    for (int q = 0; q < 4; ++q) {
      int k = tid * 4 + q;
      float uk = u[k], vk = v[k];
      float ds = digamma_f(uk + vk);
      eb[q]  = digamma_f(uk) - ds;
      e1b[q] = digamma_f(vk) - ds;
      klb[q] = lgammaf(uk + vk) - lgammaf(uk) - lgammaf(vk)
             - (lgammaf(1.0f + ALPHA_DP) - lgammaf(ALPHA_DP))
             + (uk - 1.0f) * eb[q] + (vk - ALPHA_DP) * e1b[q];
    }
    float sum4 = e1b[0] + e1b[1] + e1b[2] + e1b[3];
    float sc = sum4;
    #pragma unroll
    for (int off = 1; off < 64; off <<= 1) {
      float vv = __shfl_up(sc, off, 64);
      if (tid >= off) sc += vv;
    }
    float pre = sc - sum4;                       // exclusive prefix
    ws[OFF_ELOGPI + 4 * tid + 0] = eb[0] + pre;  pre += e1b[0];
    ws[OFF_ELOGPI + 4 * tid + 1] = eb[1] + pre;  pre += e1b[1];
    ws[OFF_ELOGPI + 4 * tid + 2] = eb[2] + pre;  pre += e1b[2];
    ws[OFF_ELOGPI + 4 * tid + 3] = eb[3] + pre;
    float ks = klb[0] + klb[1] + klb[2] + klb[3];
    #pragma unroll
    for (int off = 32; off; off >>= 1) ks += __shfl_xor(ks, off, 64);
    if (tid == 0) ws[OFF_KLB] = ks;
    return;
  }

  // ---- W-split block (one cluster) ----
  const int k = blockIdx.x, d = tid;
  _Float16* Wp = (_Float16*)ws;

  float nk = n[k], ck = c[k], n0k = n0[k], c0k = c0[k];
  float Bkd = B[k * DDIM + d],   tkd  = tau[k * DDIM + d];
  float B0kd = B0[k * DDIM + d], t0kd = tau0[k * DDIM + d];
  float Elam = nk / Bkd;
  float wb = Elam * tkd;        // coeff of x   (krow d)
  float wa = -0.5f * Elam;      // coeff of x^2 (krow 64+d)

  const int ct = k & 7, col = k >> 3;
  int   kks[2] = { d, 64 + d };
  float wvs[2] = { wb, wa };
  #pragma unroll
  for (int q = 0; q < 2; ++q) {
    int kk = kks[q]; float wq = wvs[q];
    int s = kk >> 4, rem = kk & 15, h = rem >> 3, e = rem & 7;
    int lanei = col + h * 32;
    _Float16 hi = (_Float16)wq, lo = (_Float16)(wq - (float)hi);
    Wp[( s * 8 + ct)     * 512 + lanei * 8 + e] = hi;
    Wp[(64 + s * 8 + ct) * 512 + lanei * 8 + e] = lo;
  }

  float a = 0.5f * nk, a0 = 0.5f * n0k;
  float dga = digamma_f(a);
  float lga = lgammaf(a), lga0 = lgammaf(a0);
  float b = 0.5f * Bkd, b0 = 0.5f * B0kd;
  float klg = (a - a0) * dga - lga + lga0
            + a0 * (logf(b) - logf(b0)) + a * (b0 - b) / b;
  float dt = tkd - t0kd;
  float knq = Elam * dt * dt;
  float negLogB = -logf(Bkd);
  float et2 = Elam * tkd * tkd;

  #pragma unroll
  for (int off = 32; off; off >>= 1) {
    klg     += __shfl_xor(klg, off, 64);
    knq     += __shfl_xor(knq, off, 64);
    negLogB += __shfl_xor(negLogB, off, 64);
    et2     += __shfl_xor(et2, off, 64);
  }
  if (d == 0) {
    float sumEloglam = (float)DDIM * (dga + LN2_F) + negLogB;
    ws[OFF_BASE + k] = 0.5f * (sumEloglam - (float)DDIM * LOG2PI_F
                               - (float)DDIM / ck - et2);   // NO elogpi here
    float kln = 0.5f * (float)DDIM * (c0k / ck - 1.0f + logf(ck / c0k))
              + 0.5f * c0k * knq;
    ws[OFF_KLP + k] = klg + kln;
  }
}

__device__ __forceinline__ void split8(const float* v, f16x8& h, f16x8& l) {
  #pragma unroll
  for (int e = 0; e < 8; ++e) {
    _Float16 hh = (_Float16)v[e];
    h[e] = hh;
    l[e] = (_Float16)(v[e] - (float)hh);
  }
}

// direct global->LDS DMA, 16B per lane; LDS dest = wave-uniform base + lane*16
__device__ __forceinline__ void gload16(const _Float16* g, _Float16* l) {
  __builtin_amdgcn_global_load_lds(
      reinterpret_cast<const __attribute__((address_space(1))) uint32_t*>(
          reinterpret_cast<uintptr_t>(g)),
      reinterpret_cast<__attribute__((address_space(3))) uint32_t*>(
          reinterpret_cast<uintptr_t>(l)),
      16, 0, 0);
}

// Col-split occupancy kernel: 4 waves/block; wave (rg=w&1, q=w>>1) computes
// rows [rg*32,+32) x clusters with tile ct in [4q, 4q+4) -> acc[4] = 64 AGPR
// (R18 counters: acc[8] = 236 unified regs = hard 2 waves/SIMD; this targets
// 3/SIMD at cap 170). W staged in 8x 16KB chunks double-buffered (32 KB LDS
// -> 3 blocks/CU co-resident). Softmax col-halves combined via 1KB LDS
// exchange. Fin SEPARATE (R18: device-fence fin = L2-writeback disaster).
__global__ __launch_bounds__(256, 3) void dpmm_mfma(
    const float* __restrict__ x, const _Float16* __restrict__ Wp,
    const float* __restrict__ base, const float* __restrict__ elogpi,
    float* __restrict__ pi, float* __restrict__ partial) {
  __shared__ _Float16 W_sh[2][8192];            // 2 x 16KB chunk buffers
  __shared__ float ex_m[2][64], ex_s[2][64];    // per-row (m,s) per col-half
  const int tid  = threadIdx.x;
  const int lane = tid & 63;
  const int w    = tid >> 6;
  const int rg   = w & 1;                       // row group
  const int q    = w >> 1;                      // col half
  const int col  = lane & 31;                   // tile col / A row
  const int h    = lane >> 5;                   // k-half

  // ---- x loads first (in flight during chunk0 DMA) ----
  const long row0 = (long)blockIdx.x * ROWS_PER_BLK + (long)rg * 32;
  const float* xr = x + (row0 + col) * DDIM + h * 8;
  float4 xa[4], xb[4];
  #pragma unroll
  for (int s = 0; s < 4; ++s) {
    xa[s] = *(const float4*)(xr + s * 16);
    xb[s] = *(const float4*)(xr + s * 16 + 4);
  }

  // ---- issue chunk0 DMA (16KB: 4 sweeps x 256 threads x 16B) ----
  #pragma unroll
  for (int i = 0; i < 4; ++i)
    gload16(Wp + (size_t)(i * 256 + tid) * 8, &W_sh[0][(i * 256 + w * 64) * 8]);

  // ---- A fragments: s=0..3 x, s=4..7 x^2 (hi/lo) ----
  f16x8 ah[8], al[8];
  #pragma unroll
  for (int s = 0; s < 4; ++s) {
    float cv[8] = {xa[s].x,xa[s].y,xa[s].z,xa[s].w,xb[s].x,xb[s].y,xb[s].z,xb[s].w};
    float qv[8];
    #pragma unroll
    for (int e = 0; e < 8; ++e) qv[e] = cv[e] * cv[e];
    split8(cv, ah[s], al[s]);
    split8(qv, ah[s + 4], al[s + 4]);
  }

  // ---- acc init: base + elogpi; acc[t4] = cluster col*8 + 4q + t4 ----
  f32x16 acc[4];
  {
    float4 b0 = *(const float4*)(base + col * 8 + 4 * q);
    float4 e0 = *(const float4*)(elogpi + col * 8 + 4 * q);
    float bb[4] = {b0.x+e0.x, b0.y+e0.y, b0.z+e0.z, b0.w+e0.w};
    #pragma unroll
    for (int t4 = 0; t4 < 4; ++t4) {
      #pragma unroll
      for (int j = 0; j < 16; ++j) acc[t4][j] = bb[t4];
    }
  }

  __syncthreads();                              // chunk0 landed

  // ---- chunk loop: chunk c GEMM || chunk c+1 DMA ----
  // chunk c<4: Wh s={2c,2c+1} (ah+al); c>=4: Wl s={2(c-4),2(c-4)+1} (ah)
  #pragma unroll
  for (int c = 0; c < 8; ++c) {
    if (c + 1 < 8) {
      #pragma unroll
      for (int i = 0; i < 4; ++i)
        gload16(Wp + (size_t)(c + 1) * 8192 + (size_t)(i * 256 + tid) * 8,
                &W_sh[(c + 1) & 1][(i * 256 + w * 64) * 8]);
    }
    const _Float16* Ws = W_sh[c & 1];
    const int sbase = (c < 4) ? 2 * c : 2 * (c - 4);
    #pragma unroll
    for (int sl = 0; sl < 2; ++sl) {
      const int s = sbase + sl;
      #pragma unroll
      for (int t4 = 0; t4 < 4; ++t4) {
        const int lfi = sl * 8 + 4 * q + t4;    // frag within chunk
        f16x8 b = *(const f16x8*)&Ws[(size_t)lfi * 512 + lane * 8];
        acc[t4] = __builtin_amdgcn_mfma_f32_32x32x16_f16(ah[s], b, acc[t4], 0, 0, 0);
        if (c < 4)
          acc[t4] = __builtin_amdgcn_mfma_f32_32x32x16_f16(al[s], b, acc[t4], 0, 0, 0);
      }
    }
    if (c + 1 < 8) __syncthreads();             // drains chunk c+1 DMA
  }

  // ---- epilogue pass 1: local (m,s) over this wave's 128 cols -> LDS ----
  #pragma unroll
  for (int j = 0; j < 16; ++j) {
    const int r = (j & 3) + 8 * (j >> 2) + 4 * h;
    float m = fmaxf(fmaxf(acc[0][j], acc[1][j]), fmaxf(acc[2][j], acc[3][j]));
    m = fmaxf(m, __shfl_xor(m, 1, 64));
    m = fmaxf(m, __shfl_xor(m, 2, 64));
    m = fmaxf(m, __shfl_xor(m, 4, 64));
    m = fmaxf(m, __shfl_xor(m, 8, 64));
    m = fmaxf(m, __shfl_xor(m, 16, 64));
    float s = __expf(acc[0][j] - m) + __expf(acc[1][j] - m)
            + __expf(acc[2][j] - m) + __expf(acc[3][j] - m);
    s += __shfl_xor(s, 1, 64);
    s += __shfl_xor(s, 2, 64);
    s += __shfl_xor(s, 4, 64);
    s += __shfl_xor(s, 8, 64);
    s += __shfl_xor(s, 16, 64);
    if (col == 0) { ex_m[q][rg * 32 + r] = m; ex_s[q][rg * 32 + r] = s; }
  }
  __syncthreads();

  // ---- epilogue pass 2: combine halves, write pi ----
  float wls = 0.0f;
  #pragma unroll
  for (int j = 0; j < 16; ++j) {
    const int r = (j & 3) + 8 * (j >> 2) + 4 * h;
    const int rb = rg * 32 + r;
    float m1 = ex_m[0][rb], s1 = ex_s[0][rb];
    float m2 = ex_m[1][rb], s2 = ex_s[1][rb];
    float gm = fmaxf(m1, m2);
    float gs = s1 * __expf(m1 - gm) + s2 * __expf(m2 - gm);
    float rs = 1.0f / gs;
    f32x4 pv = { __expf(acc[0][j] - gm) * rs, __expf(acc[1][j] - gm) * rs,
                 __expf(acc[2][j] - gm) * rs, __expf(acc[3][j] - gm) * rs };
    *(f32x4*)(pi + (size_t)(row0 + r) * KCL + col * 8 + 4 * q) = pv;
    wls += gm + __logf(gs);
  }
  if (q == 0) {
    // lanes cover 2 h-halves x 16 rows = 32 rows, replicated over 32 cols
    wls += __shfl_xor(wls, 1, 64);
    wls += __shfl_xor(wls, 2, 64);
    wls += __shfl_xor(wls, 4, 64);
    wls += __shfl_xor(wls, 8, 64);
    wls += __shfl_xor(wls, 16, 64);
    wls += __shfl_xor(wls, 32, 64);
    if (lane == 0) partial[blockIdx.x * 2 + rg] = wls * 0.03125f; // /32 cols
  }
}

__global__ void dpmm_fin(const float* __restrict__ ws,
                         float* __restrict__ out_elbo) {
  __shared__ double red[256];
  const int t = threadIdx.x;
  double s = 0.0;
  for (int i = t; i < NPART; i += 256) s += (double)ws[OFF_PART + i];
  s -= (double)ws[OFF_KLP + t];
  red[t] = s;
  __syncthreads();
  for (int off = 128; off; off >>= 1) {
    if (t < off) red[t] += red[t + off];
    __syncthreads();
  }
  if (t == 0) out_elbo[0] = (float)(red[0] - (double)ws[OFF_KLB]);
}

extern "C" void kernel_launch(void* const* d_in, const int* in_sizes, int n_in,
                              void* d_out, int out_size, void* d_ws, size_t ws_size,
                              hipStream_t stream) {
  const float* x    = (const float*)d_in[0];
  const float* u    = (const float*)d_in[1];
  const float* v    = (const float*)d_in[2];
  const float* tau  = (const float*)d_in[3];
  const float* c    = (const float*)d_in[4];
  const float* n    = (const float*)d_in[5];
  const float* B    = (const float*)d_in[6];
  const float* tau0 = (const float*)d_in[7];
  const float* c0   = (const float*)d_in[8];
  const float* n0   = (const float*)d_in[9];
  const float* B0   = (const float*)d_in[10];

  float* out = (float*)d_out;
  float* ws  = (float*)d_ws;

  dpmm_prep<<<KCL + 1, 64, 0, stream>>>(u, v, tau, c, n, B, tau0, c0, n0, B0, ws);

  const _Float16* Wp  = (const _Float16*)ws;
  const float* base   = ws + OFF_BASE;
  const float* elogpi = ws + OFF_ELOGPI;
  float* partial      = ws + OFF_PART;

  dpmm_mfma<<<NBLK_MAIN, 256, 0, stream>>>(x, Wp, base, elogpi, out, partial);
  dpmm_fin<<<1, 256, 0, stream>>>(ws, out + (size_t)NPTS * KCL);
}

// Round 21
// 116.676 us; speedup vs baseline: 2.4363x; 1.3613x over previous
//
#include <hip/hip_runtime.h>
#include <math.h>
#include <stdint.h>

#define NPTS 262144
#define KCL  256
#define DDIM 64
#define ALPHA_DP 1.0f

#define ROWS_PER_WAVE 32
#define WAVES_PER_BLK 4
#define ROWS_PER_BLK  (ROWS_PER_WAVE * WAVES_PER_BLK)   // 128
#define NBLK_MAIN     (NPTS / ROWS_PER_BLK)             // 2048
#define NPART         (NPTS / ROWS_PER_WAVE)            // 8192

// ws float offsets
#define OFF_ELOGPI 32768
#define OFF_BASE   33024
#define OFF_KLB    33280
#define OFF_KLP    33281
#define OFF_PART   33537

#define LN2_F    0.6931471805599453f
#define LOG2PI_F 1.8378770664093453f

typedef _Float16 f16x8  __attribute__((ext_vector_type(8)));
typedef float    f32x4  __attribute__((ext_vector_type(4)));
typedef float    f32x16 __attribute__((ext_vector_type(16)));

__device__ __forceinline__ float digamma_f(float x) {
  float r = 0.0f;
  while (x < 6.0f) { r -= 1.0f / x; x += 1.0f; }
  float inv  = 1.0f / x;
  float inv2 = inv * inv;
  return r + logf(x) - 0.5f * inv
       - inv2 * (0.083333333333333333f
         - inv2 * (0.008333333333333333f
           - inv2 * 0.003968253968253968f));
}

// --- fused prep (one launch): blocks 0..255 W-split, block 256 beta --------
// Frag layout: frag fi (0..63 Wh, 64..127 Wl), fi%64 = s*8 + ct, s=krow>>4.
//   element: Wp[fi*512 + lane*8 + e];  b-frag: col=lane&31, k=(lane>>5)*8+e
// Cluster k at tile ct=k&7, col=k>>3 -> lane owns 8 contiguous pi columns.
__global__ __launch_bounds__(64) void dpmm_prep(
    const float* __restrict__ u,   const float* __restrict__ v,
    const float* __restrict__ tau, const float* __restrict__ c,
    const float* __restrict__ n,   const float* __restrict__ B,
    const float* __restrict__ tau0, const float* __restrict__ c0,
    const float* __restrict__ n0,  const float* __restrict__ B0,
    float* __restrict__ ws) {
  const int tid = threadIdx.x;

  if (blockIdx.x == KCL) {
    // ---- beta block: thread t owns clusters 4t..4t+3 ----
    float eb[4], e1b[4], klb[4];
    #pragma unroll
    for (int q = 0; q < 4; ++q) {
      int k = tid * 4 + q;
      float uk = u[k], vk = v[k];
      float ds = digamma_f(uk + vk);
      eb[q]  = digamma_f(uk) - ds;
      e1b[q] = digamma_f(vk) - ds;
      klb[q] = lgammaf(uk + vk) - lgammaf(uk) - lgammaf(vk)
             - (lgammaf(1.0f + ALPHA_DP) - lgammaf(ALPHA_DP))
             + (uk - 1.0f) * eb[q] + (vk - ALPHA_DP) * e1b[q];
    }
    float sum4 = e1b[0] + e1b[1] + e1b[2] + e1b[3];
    float sc = sum4;
    #pragma unroll
    for (int off = 1; off < 64; off <<= 1) {
      float vv = __shfl_up(sc, off, 64);
      if (tid >= off) sc += vv;
    }
    float pre = sc - sum4;                       // exclusive prefix
    ws[OFF_ELOGPI + 4 * tid + 0] = eb[0] + pre;  pre += e1b[0];
    ws[OFF_ELOGPI + 4 * tid + 1] = eb[1] + pre;  pre += e1b[1];
    ws[OFF_ELOGPI + 4 * tid + 2] = eb[2] + pre;  pre += e1b[2];
    ws[OFF_ELOGPI + 4 * tid + 3] = eb[3] + pre;
    float ks = klb[0] + klb[1] + klb[2] + klb[3];
    #pragma unroll
    for (int off = 32; off; off >>= 1) ks += __shfl_xor(ks, off, 64);
    if (tid == 0) ws[OFF_KLB] = ks;
    return;
  }

  // ---- W-split block (one cluster) ----
  const int k = blockIdx.x, d = tid;
  _Float16* Wp = (_Float16*)ws;

  float nk = n[k], ck = c[k], n0k = n0[k], c0k = c0[k];
  float Bkd = B[k * DDIM + d],   tkd  = tau[k * DDIM + d];
  float B0kd = B0[k * DDIM + d], t0kd = tau0[k * DDIM + d];
  float Elam = nk / Bkd;
  float wb = Elam * tkd;        // coeff of x   (krow d)
  float wa = -0.5f * Elam;      // coeff of x^2 (krow 64+d)

  const int ct = k & 7, col = k >> 3;
  int   kks[2] = { d, 64 + d };
  float wvs[2] = { wb, wa };
  #pragma unroll
  for (int q = 0; q < 2; ++q) {
    int kk = kks[q]; float wq = wvs[q];
    int s = kk >> 4, rem = kk & 15, h = rem >> 3, e = rem & 7;
    int lanei = col + h * 32;
    _Float16 hi = (_Float16)wq, lo = (_Float16)(wq - (float)hi);
    Wp[( s * 8 + ct)     * 512 + lanei * 8 + e] = hi;
    Wp[(64 + s * 8 + ct) * 512 + lanei * 8 + e] = lo;
  }

  float a = 0.5f * nk, a0 = 0.5f * n0k;
  float dga = digamma_f(a);
  float lga = lgammaf(a), lga0 = lgammaf(a0);
  float b = 0.5f * Bkd, b0 = 0.5f * B0kd;
  float klg = (a - a0) * dga - lga + lga0
            + a0 * (logf(b) - logf(b0)) + a * (b0 - b) / b;
  float dt = tkd - t0kd;
  float knq = Elam * dt * dt;
  float negLogB = -logf(Bkd);
  float et2 = Elam * tkd * tkd;

  #pragma unroll
  for (int off = 32; off; off >>= 1) {
    klg     += __shfl_xor(klg, off, 64);
    knq     += __shfl_xor(knq, off, 64);
    negLogB += __shfl_xor(negLogB, off, 64);
    et2     += __shfl_xor(et2, off, 64);
  }
  if (d == 0) {
    float sumEloglam = (float)DDIM * (dga + LN2_F) + negLogB;
    ws[OFF_BASE + k] = 0.5f * (sumEloglam - (float)DDIM * LOG2PI_F
                               - (float)DDIM / ck - et2);   // NO elogpi here
    float kln = 0.5f * (float)DDIM * (c0k / ck - 1.0f + logf(ck / c0k))
              + 0.5f * c0k * knq;
    ws[OFF_KLP + k] = klg + kln;
  }
}

__device__ __forceinline__ void split8(const float* v, f16x8& h, f16x8& l) {
  #pragma unroll
  for (int e = 0; e < 8; ++e) {
    _Float16 hh = (_Float16)v[e];
    h[e] = hh;
    l[e] = (_Float16)(v[e] - (float)hh);
  }
}

// direct global->LDS DMA, 16B per lane; LDS dest = wave-uniform base + lane*16
__device__ __forceinline__ void gload16(const _Float16* g, _Float16* l) {
  __builtin_amdgcn_global_load_lds(
      reinterpret_cast<const __attribute__((address_space(1))) uint32_t*>(
          reinterpret_cast<uintptr_t>(g)),
      reinterpret_cast<__attribute__((address_space(3))) uint32_t*>(
          reinterpret_cast<uintptr_t>(l)),
      16, 0, 0);
}

// R16 main (verified best: total 114.9us): 32x32x16 MFMA, 32 rows/wave,
// W staged via global_load_lds in 4x 32KB chunks double-buffered (64 KB LDS,
// 2 blocks/CU). R21 adds T5 s_setprio around MFMA clusters: with 2 desynced
// blocks/CU, compute-phase waves get priority over DMA/epilogue waves.
// Ledger of measured dead-ends: col-split occupancy (R20 -40%), 1-block/CU
// (R17 -7%), register-persistent (R11/R15 spill), fused fin (R18 fence
// disaster), NT interleaved stores (R7 -3x).
__global__ __launch_bounds__(256, 2) void dpmm_mfma(
    const float* __restrict__ x, const _Float16* __restrict__ Wp,
    const float* __restrict__ base, const float* __restrict__ elogpi,
    float* __restrict__ pi, float* __restrict__ partial) {
  __shared__ _Float16 W_sh[2][16384];           // 2 x 32KB chunk buffers
  const int tid  = threadIdx.x;
  const int lane = tid & 63;
  const int w    = tid >> 6;
  const int col  = lane & 31;                   // tile col / A row
  const int h    = lane >> 5;                   // k-half

  // ---- x loads first (in flight during chunk0 DMA) ----
  const long row0 = (long)blockIdx.x * ROWS_PER_BLK + (long)w * ROWS_PER_WAVE;
  const float* xr = x + (row0 + col) * DDIM + h * 8;
  float4 xa[4], xb[4];
  #pragma unroll
  for (int s = 0; s < 4; ++s) {
    xa[s] = *(const float4*)(xr + s * 16);
    xb[s] = *(const float4*)(xr + s * 16 + 4);
  }

  // ---- issue chunk0 DMA ----
  #pragma unroll
  for (int i = 0; i < 8; ++i)
    gload16(Wp + (i * 256 + tid) * 8, &W_sh[0][(i * 256 + w * 64) * 8]);

  // ---- A fragments: s=0..3 x, s=4..7 x^2 (hi/lo) ----
  f16x8 ah[8], al[8];
  #pragma unroll
  for (int s = 0; s < 4; ++s) {
    float cv[8] = {xa[s].x,xa[s].y,xa[s].z,xa[s].w,xb[s].x,xb[s].y,xb[s].z,xb[s].w};
    float qv[8];
    #pragma unroll
    for (int e = 0; e < 8; ++e) qv[e] = cv[e] * cv[e];
    split8(cv, ah[s], al[s]);
    split8(qv, ah[s + 4], al[s + 4]);
  }

  // ---- acc init: base + elogpi (cluster col*8+ct) ----
  f32x16 acc[8];
  {
    float4 b0 = *(const float4*)(base + col * 8);
    float4 b1 = *(const float4*)(base + col * 8 + 4);
    float4 e0 = *(const float4*)(elogpi + col * 8);
    float4 e1 = *(const float4*)(elogpi + col * 8 + 4);
    float bb[8] = {b0.x+e0.x, b0.y+e0.y, b0.z+e0.z, b0.w+e0.w,
                   b1.x+e1.x, b1.y+e1.y, b1.z+e1.z, b1.w+e1.w};
    #pragma unroll
    for (int ct = 0; ct < 8; ++ct) {
      #pragma unroll
      for (int j = 0; j < 16; ++j) acc[ct][j] = bb[ct];
    }
  }

  __syncthreads();                              // chunk0 landed

  // ---- chunk loop: chunk c GEMM || chunk c+1 DMA ----
  // chunk 0: Wh s=0..3 (ah+al) | 1: Wh s=4..7 (ah+al) | 2: Wl s=0..3 (ah) |
  // 3: Wl s=4..7 (ah)
  #pragma unroll
  for (int c = 0; c < 4; ++c) {
    if (c + 1 < 4) {
      #pragma unroll
      for (int i = 0; i < 8; ++i)
        gload16(Wp + (size_t)(c + 1) * 16384 + (i * 256 + tid) * 8,
                &W_sh[(c + 1) & 1][(i * 256 + w * 64) * 8]);
    }
    const _Float16* Ws = W_sh[c & 1];
    __builtin_amdgcn_s_setprio(1);              // T5: favor MFMA-phase waves
    #pragma unroll
    for (int f = 0; f < 32; ++f) {
      const int ss = f >> 3, ct = f & 7;
      f16x8 b = *(const f16x8*)&Ws[f * 512 + lane * 8];
      if (c == 0) {
        acc[ct] = __builtin_amdgcn_mfma_f32_32x32x16_f16(ah[ss], b, acc[ct], 0, 0, 0);
        acc[ct] = __builtin_amdgcn_mfma_f32_32x32x16_f16(al[ss], b, acc[ct], 0, 0, 0);
      } else if (c == 1) {
        acc[ct] = __builtin_amdgcn_mfma_f32_32x32x16_f16(ah[4 + ss], b, acc[ct], 0, 0, 0);
        acc[ct] = __builtin_amdgcn_mfma_f32_32x32x16_f16(al[4 + ss], b, acc[ct], 0, 0, 0);
      } else if (c == 2) {
        acc[ct] = __builtin_amdgcn_mfma_f32_32x32x16_f16(ah[ss], b, acc[ct], 0, 0, 0);
      } else {
        acc[ct] = __builtin_amdgcn_mfma_f32_32x32x16_f16(ah[4 + ss], b, acc[ct], 0, 0, 0);
      }
    }
    __builtin_amdgcn_s_setprio(0);
    if (c + 1 < 4) __syncthreads();             // drains chunk c+1 DMA
  }

  // ---- softmax epilogue; reg j -> row (j&3)+8*(j>>2)+4*h, lane owns 8 cols ----
  float wls = 0.0f;
  #pragma unroll
  for (int j = 0; j < 16; ++j) {
    const int r = (j & 3) + 8 * (j >> 2) + 4 * h;
    float m = acc[0][j];
    #pragma unroll
    for (int ct = 1; ct < 8; ++ct) m = fmaxf(m, acc[ct][j]);
    m = fmaxf(m, __shfl_xor(m, 1, 64));
    m = fmaxf(m, __shfl_xor(m, 2, 64));
    m = fmaxf(m, __shfl_xor(m, 4, 64));
    m = fmaxf(m, __shfl_xor(m, 8, 64));
    m = fmaxf(m, __shfl_xor(m, 16, 64));
    float ev[8]; float s = 0.0f;
    #pragma unroll
    for (int ct = 0; ct < 8; ++ct) { ev[ct] = __expf(acc[ct][j] - m); s += ev[ct]; }
    s += __shfl_xor(s, 1, 64);
    s += __shfl_xor(s, 2, 64);
    s += __shfl_xor(s, 4, 64);
    s += __shfl_xor(s, 8, 64);
    s += __shfl_xor(s, 16, 64);
    float rs = 1.0f / s;
    float* pr = pi + (size_t)(row0 + r) * KCL + col * 8;
    f32x4 p0 = { ev[0]*rs, ev[1]*rs, ev[2]*rs, ev[3]*rs };
    f32x4 p1 = { ev[4]*rs, ev[5]*rs, ev[6]*rs, ev[7]*rs };
    *(f32x4*)(pr + 0) = p0;
    *(f32x4*)(pr + 4) = p1;
    wls += m + __logf(s);       // identical across the 32 lanes of this row
  }
  wls += __shfl_xor(wls, 1, 64);
  wls += __shfl_xor(wls, 2, 64);
  wls += __shfl_xor(wls, 4, 64);
  wls += __shfl_xor(wls, 8, 64);
  wls += __shfl_xor(wls, 16, 64);
  wls += __shfl_xor(wls, 32, 64);
  if (lane == 0) partial[blockIdx.x * WAVES_PER_BLK + w] = wls * 0.03125f; // /32
}

__global__ void dpmm_fin(const float* __restrict__ ws,
                         float* __restrict__ out_elbo) {
  __shared__ double red[256];
  const int t = threadIdx.x;
  double s = 0.0;
  for (int i = t; i < NPART; i += 256) s += (double)ws[OFF_PART + i];
  s -= (double)ws[OFF_KLP + t];
  red[t] = s;
  __syncthreads();
  for (int off = 128; off; off >>= 1) {
    if (t < off) red[t] += red[t + off];
    __syncthreads();
  }
  if (t == 0) out_elbo[0] = (float)(red[0] - (double)ws[OFF_KLB]);
}

extern "C" void kernel_launch(void* const* d_in, const int* in_sizes, int n_in,
                              void* d_out, int out_size, void* d_ws, size_t ws_size,
                              hipStream_t stream) {
  const float* x    = (const float*)d_in[0];
  const float* u    = (const float*)d_in[1];
  const float* v    = (const float*)d_in[2];
  const float* tau  = (const float*)d_in[3];
  const float* c    = (const float*)d_in[4];
  const float* n    = (const float*)d_in[5];
  const float* B    = (const float*)d_in[6];
  const float* tau0 = (const float*)d_in[7];
  const float* c0   = (const float*)d_in[8];
  const float* n0   = (const float*)d_in[9];
  const float* B0   = (const float*)d_in[10];

  float* out = (float*)d_out;
  float* ws  = (float*)d_ws;

  dpmm_prep<<<KCL + 1, 64, 0, stream>>>(u, v, tau, c, n, B, tau0, c0, n0, B0, ws);

  const _Float16* Wp  = (const _Float16*)ws;
  const float* base   = ws + OFF_BASE;
  const float* elogpi = ws + OFF_ELOGPI;
  float* partial      = ws + OFF_PART;

  dpmm_mfma<<<NBLK_MAIN, 256, 0, stream>>>(x, Wp, base, elogpi, out, partial);
  dpmm_fin<<<1, 256, 0, stream>>>(ws, out + (size_t)NPTS * KCL);
}

// Round 22
// 114.450 us; speedup vs baseline: 2.4837x; 1.0195x over previous
//
#include <hip/hip_runtime.h>
#include <math.h>
#include <stdint.h>

#define NPTS 262144
#define KCL  256
#define DDIM 64
#define ALPHA_DP 1.0f

#define ROWS_PER_WAVE 32
#define WAVES_PER_BLK 4
#define ROWS_PER_BLK  (ROWS_PER_WAVE * WAVES_PER_BLK)   // 128
#define NBLK_MAIN     (NPTS / ROWS_PER_BLK)             // 2048
#define NPART         (NPTS / ROWS_PER_WAVE)            // 8192

// ws float offsets
#define OFF_ELOGPI 32768
#define OFF_BASE   33024
#define OFF_KLB    33280
#define OFF_KLP    33281
#define OFF_PART   33537

#define LN2_F    0.6931471805599453f
#define LOG2PI_F 1.8378770664093453f

typedef _Float16 f16x8  __attribute__((ext_vector_type(8)));
typedef float    f32x4  __attribute__((ext_vector_type(4)));
typedef float    f32x16 __attribute__((ext_vector_type(16)));

__device__ __forceinline__ float digamma_f(float x) {
  float r = 0.0f;
  while (x < 6.0f) { r -= 1.0f / x; x += 1.0f; }
  float inv  = 1.0f / x;
  float inv2 = inv * inv;
  return r + logf(x) - 0.5f * inv
       - inv2 * (0.083333333333333333f
         - inv2 * (0.008333333333333333f
           - inv2 * 0.003968253968253968f));
}

// --- fused prep (one launch): blocks 0..255 W-split, block 256 beta --------
// Frag layout: frag fi (0..63 Wh, 64..127 Wl), fi%64 = s*8 + ct, s=krow>>4.
//   element: Wp[fi*512 + lane*8 + e];  b-frag: col=lane&31, k=(lane>>5)*8+e
// Cluster k at tile ct=k&7, col=k>>3 -> lane owns 8 contiguous pi columns.
__global__ __launch_bounds__(64) void dpmm_prep(
    const float* __restrict__ u,   const float* __restrict__ v,
    const float* __restrict__ tau, const float* __restrict__ c,
    const float* __restrict__ n,   const float* __restrict__ B,
    const float* __restrict__ tau0, const float* __restrict__ c0,
    const float* __restrict__ n0,  const float* __restrict__ B0,
    float* __restrict__ ws) {
  const int tid = threadIdx.x;

  if (blockIdx.x == KCL) {
    // ---- beta block: thread t owns clusters 4t..4t+3 ----
    float eb[4], e1b[4], klb[4];
    #pragma unroll
    for (int q = 0; q < 4; ++q) {
      int k = tid * 4 + q;
      float uk = u[k], vk = v[k];
      float ds = digamma_f(uk + vk);
      eb[q]  = digamma_f(uk) - ds;
      e1b[q] = digamma_f(vk) - ds;
      klb[q] = lgammaf(uk + vk) - lgammaf(uk) - lgammaf(vk)
             - (lgammaf(1.0f + ALPHA_DP) - lgammaf(ALPHA_DP))
             + (uk - 1.0f) * eb[q] + (vk - ALPHA_DP) * e1b[q];
    }
    float sum4 = e1b[0] + e1b[1] + e1b[2] + e1b[3];
    float sc = sum4;
    #pragma unroll
    for (int off = 1; off < 64; off <<= 1) {
      float vv = __shfl_up(sc, off, 64);
      if (tid >= off) sc += vv;
    }
    float pre = sc - sum4;                       // exclusive prefix
    ws[OFF_ELOGPI + 4 * tid + 0] = eb[0] + pre;  pre += e1b[0];
    ws[OFF_ELOGPI + 4 * tid + 1] = eb[1] + pre;  pre += e1b[1];
    ws[OFF_ELOGPI + 4 * tid + 2] = eb[2] + pre;  pre += e1b[2];
    ws[OFF_ELOGPI + 4 * tid + 3] = eb[3] + pre;
    float ks = klb[0] + klb[1] + klb[2] + klb[3];
    #pragma unroll
    for (int off = 32; off; off >>= 1) ks += __shfl_xor(ks, off, 64);
    if (tid == 0) ws[OFF_KLB] = ks;
    return;
  }

  // ---- W-split block (one cluster) ----
  const int k = blockIdx.x, d = tid;
  _Float16* Wp = (_Float16*)ws;

  float nk = n[k], ck = c[k], n0k = n0[k], c0k = c0[k];
  float Bkd = B[k * DDIM + d],   tkd  = tau[k * DDIM + d];
  float B0kd = B0[k * DDIM + d], t0kd = tau0[k * DDIM + d];
  float Elam = nk / Bkd;
  float wb = Elam * tkd;        // coeff of x   (krow d)
  float wa = -0.5f * Elam;      // coeff of x^2 (krow 64+d)

  const int ct = k & 7, col = k >> 3;
  int   kks[2] = { d, 64 + d };
  float wvs[2] = { wb, wa };
  #pragma unroll
  for (int q = 0; q < 2; ++q) {
    int kk = kks[q]; float wq = wvs[q];
    int s = kk >> 4, rem = kk & 15, h = rem >> 3, e = rem & 7;
    int lanei = col + h * 32;
    _Float16 hi = (_Float16)wq, lo = (_Float16)(wq - (float)hi);
    Wp[( s * 8 + ct)     * 512 + lanei * 8 + e] = hi;
    Wp[(64 + s * 8 + ct) * 512 + lanei * 8 + e] = lo;
  }

  float a = 0.5f * nk, a0 = 0.5f * n0k;
  float dga = digamma_f(a);
  float lga = lgammaf(a), lga0 = lgammaf(a0);
  float b = 0.5f * Bkd, b0 = 0.5f * B0kd;
  float klg = (a - a0) * dga - lga + lga0
            + a0 * (logf(b) - logf(b0)) + a * (b0 - b) / b;
  float dt = tkd - t0kd;
  float knq = Elam * dt * dt;
  float negLogB = -logf(Bkd);
  float et2 = Elam * tkd * tkd;

  #pragma unroll
  for (int off = 32; off; off >>= 1) {
    klg     += __shfl_xor(klg, off, 64);
    knq     += __shfl_xor(knq, off, 64);
    negLogB += __shfl_xor(negLogB, off, 64);
    et2     += __shfl_xor(et2, off, 64);
  }
  if (d == 0) {
    float sumEloglam = (float)DDIM * (dga + LN2_F) + negLogB;
    ws[OFF_BASE + k] = 0.5f * (sumEloglam - (float)DDIM * LOG2PI_F
                               - (float)DDIM / ck - et2);   // NO elogpi here
    float kln = 0.5f * (float)DDIM * (c0k / ck - 1.0f + logf(ck / c0k))
              + 0.5f * c0k * knq;
    ws[OFF_KLP + k] = klg + kln;
  }
}

__device__ __forceinline__ void split8(const float* v, f16x8& h, f16x8& l) {
  #pragma unroll
  for (int e = 0; e < 8; ++e) {
    _Float16 hh = (_Float16)v[e];
    h[e] = hh;
    l[e] = (_Float16)(v[e] - (float)hh);
  }
}

// direct global->LDS DMA, 16B per lane; LDS dest = wave-uniform base + lane*16
__device__ __forceinline__ void gload16(const _Float16* g, _Float16* l) {
  __builtin_amdgcn_global_load_lds(
      reinterpret_cast<const __attribute__((address_space(1))) uint32_t*>(
          reinterpret_cast<uintptr_t>(g)),
      reinterpret_cast<__attribute__((address_space(3))) uint32_t*>(
          reinterpret_cast<uintptr_t>(l)),
      16, 0, 0);
}

// FINAL (R16 config, best verified: 114.9us total; main ~95us).
// 32x32x16 MFMA, 32 rows/wave, W staged via global_load_lds in 4x 32KB
// chunks double-buffered (64 KB LDS, 2 blocks/CU).
// Structural ceiling: softmax over K=256 forces acc[8]=128 AGPR + 108 VGPR
// = 236 unified regs -> hard 2 waves/SIMD. Measured dead-ends: col-split
// occupancy (R20 -40%), 16x16 shape (R12 -20%), 1-block/CU (R17 -7%),
// register-persistent (R11/R15 spill), fused fin (R18 XCD-fence disaster),
// NT interleaved stores (R7 -3x), setprio (R21 null).
__global__ __launch_bounds__(256, 2) void dpmm_mfma(
    const float* __restrict__ x, const _Float16* __restrict__ Wp,
    const float* __restrict__ base, const float* __restrict__ elogpi,
    float* __restrict__ pi, float* __restrict__ partial) {
  __shared__ _Float16 W_sh[2][16384];           // 2 x 32KB chunk buffers
  const int tid  = threadIdx.x;
  const int lane = tid & 63;
  const int w    = tid >> 6;
  const int col  = lane & 31;                   // tile col / A row
  const int h    = lane >> 5;                   // k-half

  // ---- x loads first (in flight during chunk0 DMA) ----
  const long row0 = (long)blockIdx.x * ROWS_PER_BLK + (long)w * ROWS_PER_WAVE;
  const float* xr = x + (row0 + col) * DDIM + h * 8;
  float4 xa[4], xb[4];
  #pragma unroll
  for (int s = 0; s < 4; ++s) {
    xa[s] = *(const float4*)(xr + s * 16);
    xb[s] = *(const float4*)(xr + s * 16 + 4);
  }

  // ---- issue chunk0 DMA ----
  #pragma unroll
  for (int i = 0; i < 8; ++i)
    gload16(Wp + (i * 256 + tid) * 8, &W_sh[0][(i * 256 + w * 64) * 8]);

  // ---- A fragments: s=0..3 x, s=4..7 x^2 (hi/lo) ----
  f16x8 ah[8], al[8];
  #pragma unroll
  for (int s = 0; s < 4; ++s) {
    float cv[8] = {xa[s].x,xa[s].y,xa[s].z,xa[s].w,xb[s].x,xb[s].y,xb[s].z,xb[s].w};
    float qv[8];
    #pragma unroll
    for (int e = 0; e < 8; ++e) qv[e] = cv[e] * cv[e];
    split8(cv, ah[s], al[s]);
    split8(qv, ah[s + 4], al[s + 4]);
  }

  // ---- acc init: base + elogpi (cluster col*8+ct) ----
  f32x16 acc[8];
  {
    float4 b0 = *(const float4*)(base + col * 8);
    float4 b1 = *(const float4*)(base + col * 8 + 4);
    float4 e0 = *(const float4*)(elogpi + col * 8);
    float4 e1 = *(const float4*)(elogpi + col * 8 + 4);
    float bb[8] = {b0.x+e0.x, b0.y+e0.y, b0.z+e0.z, b0.w+e0.w,
                   b1.x+e1.x, b1.y+e1.y, b1.z+e1.z, b1.w+e1.w};
    #pragma unroll
    for (int ct = 0; ct < 8; ++ct) {
      #pragma unroll
      for (int j = 0; j < 16; ++j) acc[ct][j] = bb[ct];
    }
  }

  __syncthreads();                              // chunk0 landed

  // ---- chunk loop: chunk c GEMM || chunk c+1 DMA ----
  // chunk 0: Wh s=0..3 (ah+al) | 1: Wh s=4..7 (ah+al) | 2: Wl s=0..3 (ah) |
  // 3: Wl s=4..7 (ah)
  #pragma unroll
  for (int c = 0; c < 4; ++c) {
    if (c + 1 < 4) {
      #pragma unroll
      for (int i = 0; i < 8; ++i)
        gload16(Wp + (size_t)(c + 1) * 16384 + (i * 256 + tid) * 8,
                &W_sh[(c + 1) & 1][(i * 256 + w * 64) * 8]);
    }
    const _Float16* Ws = W_sh[c & 1];
    #pragma unroll
    for (int f = 0; f < 32; ++f) {
      const int ss = f >> 3, ct = f & 7;
      f16x8 b = *(const f16x8*)&Ws[f * 512 + lane * 8];
      if (c == 0) {
        acc[ct] = __builtin_amdgcn_mfma_f32_32x32x16_f16(ah[ss], b, acc[ct], 0, 0, 0);
        acc[ct] = __builtin_amdgcn_mfma_f32_32x32x16_f16(al[ss], b, acc[ct], 0, 0, 0);
      } else if (c == 1) {
        acc[ct] = __builtin_amdgcn_mfma_f32_32x32x16_f16(ah[4 + ss], b, acc[ct], 0, 0, 0);
        acc[ct] = __builtin_amdgcn_mfma_f32_32x32x16_f16(al[4 + ss], b, acc[ct], 0, 0, 0);
      } else if (c == 2) {
        acc[ct] = __builtin_amdgcn_mfma_f32_32x32x16_f16(ah[ss], b, acc[ct], 0, 0, 0);
      } else {
        acc[ct] = __builtin_amdgcn_mfma_f32_32x32x16_f16(ah[4 + ss], b, acc[ct], 0, 0, 0);
      }
    }
    if (c + 1 < 4) __syncthreads();             // drains chunk c+1 DMA
  }

  // ---- softmax epilogue; reg j -> row (j&3)+8*(j>>2)+4*h, lane owns 8 cols ----
  float wls = 0.0f;
  #pragma unroll
  for (int j = 0; j < 16; ++j) {
    const int r = (j & 3) + 8 * (j >> 2) + 4 * h;
    float m = acc[0][j];
    #pragma unroll
    for (int ct = 1; ct < 8; ++ct) m = fmaxf(m, acc[ct][j]);
    m = fmaxf(m, __shfl_xor(m, 1, 64));
    m = fmaxf(m, __shfl_xor(m, 2, 64));
    m = fmaxf(m, __shfl_xor(m, 4, 64));
    m = fmaxf(m, __shfl_xor(m, 8, 64));
    m = fmaxf(m, __shfl_xor(m, 16, 64));
    float ev[8]; float s = 0.0f;
    #pragma unroll
    for (int ct = 0; ct < 8; ++ct) { ev[ct] = __expf(acc[ct][j] - m); s += ev[ct]; }
    s += __shfl_xor(s, 1, 64);
    s += __shfl_xor(s, 2, 64);
    s += __shfl_xor(s, 4, 64);
    s += __shfl_xor(s, 8, 64);
    s += __shfl_xor(s, 16, 64);
    float rs = 1.0f / s;
    float* pr = pi + (size_t)(row0 + r) * KCL + col * 8;
    f32x4 p0 = { ev[0]*rs, ev[1]*rs, ev[2]*rs, ev[3]*rs };
    f32x4 p1 = { ev[4]*rs, ev[5]*rs, ev[6]*rs, ev[7]*rs };
    *(f32x4*)(pr + 0) = p0;
    *(f32x4*)(pr + 4) = p1;
    wls += m + __logf(s);       // identical across the 32 lanes of this row
  }
  wls += __shfl_xor(wls, 1, 64);
  wls += __shfl_xor(wls, 2, 64);
  wls += __shfl_xor(wls, 4, 64);
  wls += __shfl_xor(wls, 8, 64);
  wls += __shfl_xor(wls, 16, 64);
  wls += __shfl_xor(wls, 32, 64);
  if (lane == 0) partial[blockIdx.x * WAVES_PER_BLK + w] = wls * 0.03125f; // /32
}

__global__ void dpmm_fin(const float* __restrict__ ws,
                         float* __restrict__ out_elbo) {
  __shared__ double red[256];
  const int t = threadIdx.x;
  double s = 0.0;
  for (int i = t; i < NPART; i += 256) s += (double)ws[OFF_PART + i];
  s -= (double)ws[OFF_KLP + t];
  red[t] = s;
  __syncthreads();
  for (int off = 128; off; off >>= 1) {
    if (t < off) red[t] += red[t + off];
    __syncthreads();
  }
  if (t == 0) out_elbo[0] = (float)(red[0] - (double)ws[OFF_KLB]);
}

extern "C" void kernel_launch(void* const* d_in, const int* in_sizes, int n_in,
                              void* d_out, int out_size, void* d_ws, size_t ws_size,
                              hipStream_t stream) {
  const float* x    = (const float*)d_in[0];
  const float* u    = (const float*)d_in[1];
  const float* v    = (const float*)d_in[2];
  const float* tau  = (const float*)d_in[3];
  const float* c    = (const float*)d_in[4];
  const float* n    = (const float*)d_in[5];
  const float* B    = (const float*)d_in[6];
  const float* tau0 = (const float*)d_in[7];
  const float* c0   = (const float*)d_in[8];
  const float* n0   = (const float*)d_in[9];
  const float* B0   = (const float*)d_in[10];

  float* out = (float*)d_out;
  float* ws  = (float*)d_ws;

  dpmm_prep<<<KCL + 1, 64, 0, stream>>>(u, v, tau, c, n, B, tau0, c0, n0, B0, ws);

  const _Float16* Wp  = (const _Float16*)ws;
  const float* base   = ws + OFF_BASE;
  const float* elogpi = ws + OFF_ELOGPI;
  float* partial      = ws + OFF_PART;

  dpmm_mfma<<<NBLK_MAIN, 256, 0, stream>>>(x, Wp, base, elogpi, out, partial);
  dpmm_fin<<<1, 256, 0, stream>>>(ws, out + (size_t)NPTS * KCL);
}